// Round 13
// baseline (704.269 us; speedup 1.0000x reference)
//
#include <hip/hip_runtime.h>
#include <math.h>

#define BATCH 8
#define NCELLS 196
#define NCLS 20
#define HEADC 25

typedef __attribute__((ext_vector_type(8))) short short8;
typedef __attribute__((ext_vector_type(4))) float f32x4;
#define MFMA16(a,b,c) __builtin_amdgcn_mfma_f32_16x16x32_bf16(a,b,c,0,0,0)

// ---- bf16 split helpers (RNE via bit ops; deterministic) ----
__device__ __forceinline__ unsigned short f2bf(float x) {
    union { float f; unsigned u; } a; a.f = x;
    unsigned r = a.u + 0x7FFFu + ((a.u >> 16) & 1u);
    return (unsigned short)(r >> 16);
}
__device__ __forceinline__ float bf2f(unsigned short h) {
    union { unsigned u; float f; } a; a.u = ((unsigned)h) << 16;
    return a.f;
}
__device__ __forceinline__ void split_bf(float x, unsigned short& h, unsigned short& l) {
    h = f2bf(x);
    l = f2bf(x - bf2f(h));
}

// ---- merged weight prep: conv2..conv5 in ONE launch ----
__device__ __forceinline__ void prep_one(const float* __restrict__ w, int CIN, int COUT,
                                         int idx, unsigned short* __restrict__ whi,
                                         unsigned short* __restrict__ wlo) {
    int G = COUT >> 4, CH = CIN >> 5;
    int j    = idx & 7;
    int lane = (idx >> 3) & 63;
    int fg   = idx >> 9;
    int g    = fg % G;
    int fc   = fg / G;
    int chunk = fc % CH;
    int plane = fc / CH;
    int co = g * 16 + (lane & 15);
    int ci = chunk * 32 + (lane >> 4) * 8 + j;
    int ky = plane / 3, kx = plane % 3;
    float v = w[((co * CIN + ci) * 3 + ky) * 3 + kx];
    unsigned short h, l; split_bf(v, h, l);
    whi[idx] = h; wlo[idx] = l;
}
__global__ void prep_all(const float* __restrict__ w2, const float* __restrict__ w3,
                         const float* __restrict__ w4, const float* __restrict__ w5,
                         unsigned short* __restrict__ w2h, unsigned short* __restrict__ w2l,
                         unsigned short* __restrict__ w3h, unsigned short* __restrict__ w3l,
                         unsigned short* __restrict__ w4h, unsigned short* __restrict__ w4l,
                         unsigned short* __restrict__ w5h, unsigned short* __restrict__ w5l) {
    int idx = blockIdx.x * 256 + threadIdx.x;
    const int n2 = 73728, n3 = 294912, n4 = 1179648, n5 = 2359296;
    if (idx < n2) { prep_one(w2, 64, 128, idx, w2h, w2l); return; }
    idx -= n2;
    if (idx < n3) { prep_one(w3, 128, 256, idx, w3h, w3l); return; }
    idx -= n3;
    if (idx < n4) { prep_one(w4, 256, 512, idx, w4h, w4l); return; }
    idx -= n4;
    if (idx < n5) { prep_one(w5, 512, 512, idx, w5h, w5l); }
}

// ---- R13: conv1 fused into conv2, quad-vectorized conv1 phase ----
// Thread = (pixel-quad, co-group-of-8): per (ci,ky) the 12 covering x values
// come from 3 aligned float4 LDS reads, reused across kx and 4 pixels.
// LDS ops per 864 FMA: ~30 b128 (was ~81 mixed) — R12's LDS-pipe saturation
// (VALUBusy 40% was mostly LDS-wait) drops ~3x.
// LDS = 36,992(sA) + 20,160(sX, 48-col pad) + 6,912(sW1) = 64,064 B -> 2 blocks/CU.
__launch_bounds__(256, 2)
__global__ void conv2_fused(const float* __restrict__ x, const float* __restrict__ w1,
                            const unsigned short* __restrict__ whi, const unsigned short* __restrict__ wlo,
                            unsigned short* __restrict__ ohi, unsigned short* __restrict__ olo) {
    constexpr int PLANE_E = 17 * 17 * 32;
    __shared__ __align__(16) unsigned short sA[2 * PLANE_E];
    __shared__ __align__(16) float sX[3][35][48];
    __shared__ float sW1[27][64];

    int bid = blockIdx.x;
    int txi = bid % 14;  bid /= 14;
    int tyi = bid % 14;
    int b   = bid / 14;
    int oy0 = tyi * 8, ox0 = txi * 8;       // conv2 out origin
    int ay0 = oy0 * 2, ax0 = ox0 * 2;       // a1 tile origin (17x17)
    int xy0 = ay0 * 2, xx0 = ax0 * 2;       // x tile origin (35x35)

    int tid = threadIdx.x;
    int w   = tid >> 6;
    int lane = tid & 63;
    int n = lane & 15, quad = lane >> 4;

    // stage w1 [27][64]
    for (int e = tid; e < 1728; e += 256)
        sW1[e >> 6][e & 63] = w1[(e & 63) * 27 + (e >> 6)];
    // stage x tile [3][35][35] into 48-col padded rows
    for (int e = tid; e < 3675; e += 256) {
        int ci = e / 1225;
        int r  = (e / 35) % 35;
        int cx = e % 35;
        float v = 0.f;
        if (xy0 + r < 448 && xx0 + cx < 448)
            v = x[(((size_t)b * 3 + ci) * 448 + xy0 + r) * 448 + xx0 + cx];
        sX[ci][r][cx] = v;
    }
    // zero the pad cols (35..47) so quad-4 vector reads are well-defined
    for (int e = tid; e < 3 * 35 * 13; e += 256) {
        int ci = e / (35 * 13);
        int r  = (e / 13) % 35;
        int cx = 35 + (e % 13);
        sX[ci][r][cx] = 0.f;
    }

    int oyl[4], oxl[4], pbase[4];
    #pragma unroll
    for (int nt = 0; nt < 4; nt++) {
        int oy_off = (nt >> 1) * 4 + (n >> 2);
        int ox_off = (nt & 1) * 4 + (n & 3);
        oyl[nt] = oy0 + oy_off;
        oxl[nt] = ox0 + ox_off;
        pbase[nt] = 2 * oy_off * 17 + 2 * ox_off;
    }
    f32x4 zero = {0.f, 0.f, 0.f, 0.f};
    f32x4 acc[2][4];
    #pragma unroll
    for (int ct = 0; ct < 2; ct++)
        #pragma unroll
        for (int nt = 0; nt < 4; nt++) acc[ct][nt] = zero;
    int g0 = w * 2;                          // COG=1, G=8

    for (int ch = 0; ch < 2; ch++) {         // a1 channel chunks (2 x 32)
        __syncthreads();                     // sA free; (ch=0) sX/sW1 ready
        // ---- conv1 phase: 85 quads (17 rows x 5) x 4 co-groups ----
        for (int e = tid; e < 85 * 4; e += 256) {
            int g   = e & 3;
            int qi  = e >> 2;
            int liy = qi / 5;
            int q   = qi - liy * 5;
            int lix0 = q * 4;
            int co8 = ch * 32 + g * 8;
            bool rowok = (ay0 + liy < 224);
            float a0[4][8];
            #pragma unroll
            for (int d = 0; d < 4; d++)
                #pragma unroll
                for (int u = 0; u < 8; u++) a0[d][u] = 0.f;
            #pragma unroll
            for (int ci = 0; ci < 3; ci++) {
                #pragma unroll
                for (int ky = 0; ky < 3; ky++) {
                    const float* row = sX[ci][2 * liy + ky];
                    float4 xa = *(const float4*)&row[2 * lix0];
                    float4 xb = *(const float4*)&row[2 * lix0 + 4];
                    float4 xc = *(const float4*)&row[2 * lix0 + 8];
                    float xr[12] = { xa.x, xa.y, xa.z, xa.w,
                                     xb.x, xb.y, xb.z, xb.w,
                                     xc.x, xc.y, xc.z, xc.w };
                    #pragma unroll
                    for (int kx = 0; kx < 3; kx++) {
                        const float* wp = &sW1[(ci * 3 + ky) * 3 + kx][co8];
                        float4 wa = *(const float4*)wp;
                        float4 wb = *(const float4*)(wp + 4);
                        #pragma unroll
                        for (int d = 0; d < 4; d++) {
                            float xv = xr[2 * d + kx];
                            a0[d][0] += wa.x * xv; a0[d][1] += wa.y * xv;
                            a0[d][2] += wa.z * xv; a0[d][3] += wa.w * xv;
                            a0[d][4] += wb.x * xv; a0[d][5] += wb.y * xv;
                            a0[d][6] += wb.z * xv; a0[d][7] += wb.w * xv;
                        }
                    }
                }
            }
            #pragma unroll
            for (int d = 0; d < 4; d++) {
                int lix = lix0 + d;
                if (lix > 16) continue;                 // no slot in 17-wide tile
                bool ok = rowok && (ax0 + lix < 224);
                union { unsigned short u[8]; uint4 v; } ph, pl;
                if (ok) {
                    #pragma unroll
                    for (int u = 0; u < 8; u++) {
                        float v = fmaxf(a0[d][u], 0.f);
                        split_bf(v, ph.u[u], pl.u[u]);
                    }
                } else {
                    ph.v = make_uint4(0u,0u,0u,0u);
                    pl.v = make_uint4(0u,0u,0u,0u);
                }
                int pxi = liy * 17 + lix;
                int u = pxi * 4 + (g ^ ((pxi >> 1) & 3));
                *(uint4*)&sA[u * 8] = ph.v;
                *(uint4*)&sA[PLANE_E + u * 8] = pl.v;
            }
        }
        __syncthreads();
        // ---- MFMA planes (R8-exact) ----
        #pragma unroll
        for (int pl = 0; pl < 9; pl++) {
            size_t fbase = ((size_t)(pl * 2 + ch) * 8 + g0) * 512 + lane * 8;
            short8 Ah0 = *(const short8*)(whi + fbase);
            short8 Ah1 = *(const short8*)(whi + fbase + 512);
            short8 Al0 = *(const short8*)(wlo + fbase);
            short8 Al1 = *(const short8*)(wlo + fbase + 512);
            int dp = (pl / 3) * 17 + (pl % 3);
            #pragma unroll
            for (int nt = 0; nt < 4; nt++) {
                int p = pbase[nt] + dp;
                int u = p * 4 + (quad ^ ((p >> 1) & 3));
                short8 Bh = *(const short8*)&sA[u * 8];
                short8 Bl = *(const short8*)&sA[PLANE_E + u * 8];
                acc[0][nt] = MFMA16(Ah0, Bh, acc[0][nt]);
                acc[0][nt] = MFMA16(Ah0, Bl, acc[0][nt]);
                acc[0][nt] = MFMA16(Al0, Bh, acc[0][nt]);
                acc[1][nt] = MFMA16(Ah1, Bh, acc[1][nt]);
                acc[1][nt] = MFMA16(Ah1, Bl, acc[1][nt]);
                acc[1][nt] = MFMA16(Al1, Bh, acc[1][nt]);
            }
        }
    }
    int cob = w * 32;
    #pragma unroll
    for (int ct = 0; ct < 2; ct++) {
        #pragma unroll
        for (int nt = 0; nt < 4; nt++) {
            size_t base = ((size_t)(b * 112 + oyl[nt]) * 112 + oxl[nt]) * 128
                          + cob + ct * 16 + quad * 4;
            unsigned long long h64 = 0ull, l64 = 0ull;
            #pragma unroll
            for (int r = 0; r < 4; r++) {
                float v = fmaxf(acc[ct][nt][r], 0.f);
                unsigned short hh, ll; split_bf(v, hh, ll);
                h64 |= ((unsigned long long)hh) << (16 * r);
                l64 |= ((unsigned long long)ll) << (16 * r);
            }
            *(unsigned long long*)&ohi[base] = h64;
            *(unsigned long long*)&olo[base] = l64;
        }
    }
}

// ---- MFMA conv (R8-exact structure) ----
template<int CIN, int COUT, int HIN, int WIN, int KSPLIT, bool PARTIAL>
__launch_bounds__(256, 4)
__global__ void conv_mfma(const unsigned short* __restrict__ ahi, const unsigned short* __restrict__ alo,
                          const unsigned short* __restrict__ whi, const unsigned short* __restrict__ wlo,
                          unsigned short* __restrict__ ohi, unsigned short* __restrict__ olo,
                          float* __restrict__ part) {
    constexpr int HOUT = HIN / 2, WOUT = WIN / 2;
    constexpr int TX = (WOUT + 7) / 8, TY = (HOUT + 7) / 8;
    constexpr int COG = COUT / 128;
    constexpr int CH_TOT = CIN / 32;
    constexpr int CH = CH_TOT / KSPLIT;
    constexpr int G = COUT / 16;
    constexpr int PLANE_E = 17 * 17 * 32;
    constexpr size_t PSZ = (size_t)BATCH * HOUT * WOUT * COUT;

    __shared__ __align__(16) unsigned short sA[2 * PLANE_E];

    int bid = blockIdx.x;
    int ks  = bid % KSPLIT; bid /= KSPLIT;
    int txi = bid % TX;     bid /= TX;
    int tyi = bid % TY;     bid /= TY;
    int cg  = bid % COG;
    int b   = bid / COG;
    int oy0 = tyi * 8, ox0 = txi * 8;
    int iy0 = oy0 * 2, ix0 = ox0 * 2;

    int tid = threadIdx.x;
    int w   = tid >> 6;
    int lane = tid & 63;
    int n = lane & 15, quad = lane >> 4;

    int oyl[4], oxl[4], pbase[4];
    #pragma unroll
    for (int nt = 0; nt < 4; nt++) {
        int oyq = nt >> 1, oxq = nt & 1;
        int oy_off = oyq * 4 + (n >> 2);
        int ox_off = oxq * 4 + (n & 3);
        oyl[nt] = oy0 + oy_off;
        oxl[nt] = ox0 + ox_off;
        pbase[nt] = 2 * oy_off * 17 + 2 * ox_off;
    }

    f32x4 zero = {0.f, 0.f, 0.f, 0.f};
    f32x4 acc[2][4];
    #pragma unroll
    for (int ct = 0; ct < 2; ct++)
        #pragma unroll
        for (int nt = 0; nt < 4; nt++) acc[ct][nt] = zero;

    int g0 = cg * 8 + w * 2;

    for (int ch = 0; ch < CH; ch++) {
        int chunk = ks * CH + ch;
        int ci0 = chunk * 32;
        __syncthreads();
        for (int e = tid; e < 17 * 17 * 8; e += 256) {
            int pxi = e >> 3, grp = e & 7;
            int liy = pxi / 17, lix = pxi - liy * 17;
            int iy = iy0 + liy, ix = ix0 + lix;
            uint4 v = make_uint4(0u, 0u, 0u, 0u);
            if (iy < HIN && ix < WIN) {
                const unsigned short* src = ((grp & 4) ? alo : ahi)
                    + ((size_t)(b * HIN + iy) * WIN + ix) * CIN + ci0 + (grp & 3) * 8;
                v = *(const uint4*)src;
            }
            int u = pxi * 4 + ((grp & 3) ^ ((pxi >> 1) & 3));
            *(uint4*)&sA[((grp >> 2) ? PLANE_E : 0) + u * 8] = v;
        }
        __syncthreads();
        #pragma unroll
        for (int pl = 0; pl < 9; pl++) {
            size_t fbase = ((size_t)(pl * CH_TOT + chunk) * G + g0) * 512 + lane * 8;
            short8 Ah0 = *(const short8*)(whi + fbase);
            short8 Ah1 = *(const short8*)(whi + fbase + 512);
            short8 Al0 = *(const short8*)(wlo + fbase);
            short8 Al1 = *(const short8*)(wlo + fbase + 512);
            int dp = (pl / 3) * 17 + (pl % 3);
            #pragma unroll
            for (int nt = 0; nt < 4; nt++) {
                int p = pbase[nt] + dp;
                int u = p * 4 + (quad ^ ((p >> 1) & 3));
                short8 Bh = *(const short8*)&sA[u * 8];
                short8 Bl = *(const short8*)&sA[PLANE_E + u * 8];
                acc[0][nt] = MFMA16(Ah0, Bh, acc[0][nt]);
                acc[0][nt] = MFMA16(Ah0, Bl, acc[0][nt]);
                acc[0][nt] = MFMA16(Al0, Bh, acc[0][nt]);
                acc[1][nt] = MFMA16(Ah1, Bh, acc[1][nt]);
                acc[1][nt] = MFMA16(Ah1, Bl, acc[1][nt]);
                acc[1][nt] = MFMA16(Al1, Bh, acc[1][nt]);
            }
        }
    }
    int cob = cg * 128 + w * 32;
    #pragma unroll
    for (int ct = 0; ct < 2; ct++) {
        #pragma unroll
        for (int nt = 0; nt < 4; nt++) {
            if (oyl[nt] >= HOUT || oxl[nt] >= WOUT) continue;
            size_t base = ((size_t)(b * HOUT + oyl[nt]) * WOUT + oxl[nt]) * COUT
                          + cob + ct * 16 + quad * 4;
            if (PARTIAL) {
                *(f32x4*)&part[(size_t)ks * PSZ + base] = acc[ct][nt];
            } else {
                unsigned long long h64 = 0ull, l64 = 0ull;
                #pragma unroll
                for (int r = 0; r < 4; r++) {
                    float v = fmaxf(acc[ct][nt][r], 0.f);
                    unsigned short hh, ll; split_bf(v, hh, ll);
                    h64 |= ((unsigned long long)hh) << (16 * r);
                    l64 |= ((unsigned long long)ll) << (16 * r);
                }
                *(unsigned long long*)&ohi[base] = h64;
                *(unsigned long long*)&olo[base] = l64;
            }
        }
    }
}

// ---- reduce KS K-split fp32 partials -> ReLU -> hi/lo bf16 ----
template<int KS>
__global__ void reduceN_split(const float* __restrict__ p, unsigned short* __restrict__ oh,
                              unsigned short* __restrict__ ol, int n) {
    int n4 = n >> 2;
    int i = blockIdx.x * 256 + threadIdx.x;
    if (i >= n4) return;
    const float4* p4 = (const float4*)p;
    float4 s = p4[i];
    #pragma unroll
    for (int k = 1; k < KS; k++) {
        float4 t = p4[i + (size_t)k * n4];
        s.x += t.x; s.y += t.y; s.z += t.z; s.w += t.w;
    }
    float v[4] = { fmaxf(s.x,0.f), fmaxf(s.y,0.f), fmaxf(s.z,0.f), fmaxf(s.w,0.f) };
    unsigned long long h64 = 0ull, l64 = 0ull;
    #pragma unroll
    for (int r = 0; r < 4; r++) {
        unsigned short hh, ll; split_bf(v[r], hh, ll);
        h64 |= ((unsigned long long)hh) << (16 * r);
        l64 |= ((unsigned long long)ll) << (16 * r);
    }
    *(unsigned long long*)&oh[i * 4] = h64;
    *(unsigned long long*)&ol[i * 4] = l64;
}

// ---- fused 1x1 head + decode ----
__global__ void head_decode_kernel(const unsigned short* __restrict__ ah,
                                   const unsigned short* __restrict__ al,
                                   const float* __restrict__ wh,
                                   float* __restrict__ out, float* __restrict__ cls) {
    int wave = threadIdx.x >> 6;
    int lane = threadIdx.x & 63;
    int cellid = blockIdx.x * 4 + wave;
    float acc[HEADC];
    #pragma unroll
    for (int c = 0; c < HEADC; c++) acc[c] = 0.f;
    for (int it = 0; it < 8; it++) {
        int ci = it * 64 + lane;
        size_t idx = (size_t)cellid * 512 + ci;
        float a = bf2f(ah[idx]) + bf2f(al[idx]);
        #pragma unroll
        for (int c = 0; c < HEADC; c++) acc[c] += a * wh[c * 512 + ci];
    }
    #pragma unroll
    for (int c = 0; c < HEADC; c++) {
        float v = acc[c];
        v += __shfl_down(v, 32); v += __shfl_down(v, 16); v += __shfl_down(v, 8);
        v += __shfl_down(v, 4);  v += __shfl_down(v, 2);  v += __shfl_down(v, 1);
        acc[c] = v;
    }
    if (lane == 0) {
        int cell = cellid % NCELLS;
        int gx = cell % 14, gy = cell / 14;
        float conf = 1.f / (1.f + expf(-acc[0]));
        float m = acc[1];
        #pragma unroll
        for (int c = 1; c < NCLS; c++) m = fmaxf(m, acc[1 + c]);
        float e[NCLS], s = 0.f;
        #pragma unroll
        for (int c = 0; c < NCLS; c++) { e[c] = expf(acc[1 + c] - m); s += e[c]; }
        float inv = conf / s;
        #pragma unroll
        for (int c = 0; c < NCLS; c++) cls[(size_t)cellid * NCLS + c] = e[c] * inv;
        float cx = (1.f / (1.f + expf(-acc[21])) + gx) * 32.f;
        float cy = (1.f / (1.f + expf(-acc[22])) + gy) * 32.f;
        float bw = expf(acc[23]) * 32.f;
        float bh = expf(acc[24]) * 32.f;
        float x1 = (cx - 0.5f * bw) / 448.f, y1 = (cy - 0.5f * bh) / 448.f;
        float x2 = (cx + 0.5f * bw) / 448.f, y2 = (cy + 0.5f * bh) / 448.f;
        x1 = fminf(fmaxf(x1, 0.f), 1.f); y1 = fminf(fmaxf(y1, 0.f), 1.f);
        x2 = fminf(fmaxf(x2, 0.f), 1.f); y2 = fminf(fmaxf(y2, 0.f), 1.f);
        float* o = out + (size_t)cellid * 24;
        o[0] = x1; o[1] = y1; o[2] = x2; o[3] = y2;
    }
}

// ---- NMS with inline IoU (boxes staged in LDS) ----
__global__ void nms_kernel(const float* __restrict__ cls, const float* __restrict__ boxes,
                           float* __restrict__ out) {
    int b = blockIdx.x / NCLS;
    int c = blockIdx.x % NCLS;
    __shared__ float sc[NCELLS];
    __shared__ float ssort[NCELLS];
    __shared__ int   ord[NCELLS];
    __shared__ __align__(16) float sbox[NCELLS][4];
    __shared__ float sarea[NCELLS];
    __shared__ __align__(16) unsigned long long smask[NCELLS][4];
    int j = threadIdx.x;
    int lane = j & 63;
    int w = j >> 6;
    float sj = 0.f;
    if (j < NCELLS) {
        sj = cls[(((size_t)b * NCELLS) + j) * NCLS + c];
        sc[j] = sj;
        float4 bx = *(const float4*)&boxes[(((size_t)b * NCELLS) + j) * 24];
        *(float4*)sbox[j] = bx;
        sarea[j] = fmaxf(bx.z - bx.x, 0.f) * fmaxf(bx.w - bx.y, 0.f);
    }
    __syncthreads();
    if (j < NCELLS) {
        int r = 0;
        for (int k = 0; k < NCELLS; k++) {
            float sk = sc[k];
            r += (sk > sj) || (sk == sj && k < j);
        }
        ord[r] = j; ssort[r] = sj;
    }
    __syncthreads();
    int oc[4]; float bx1[4], by1[4], bx2[4], by2[4], bar[4];
    #pragma unroll
    for (int k = 0; k < 4; k++) {
        int cidx = k * 64 + lane;
        oc[k] = (cidx < NCELLS) ? ord[cidx] : 0;
        bx1[k] = sbox[oc[k]][0]; by1[k] = sbox[oc[k]][1];
        bx2[k] = sbox[oc[k]][2]; by2[k] = sbox[oc[k]][3];
        bar[k] = sarea[oc[k]];
    }
    for (int i = w; i < NCELLS; i += 4) {
        int oi = ord[i];
        float ix1 = sbox[oi][0], iy1 = sbox[oi][1];
        float ix2 = sbox[oi][2], iy2 = sbox[oi][3];
        float ia  = sarea[oi];
        #pragma unroll
        for (int k = 0; k < 4; k++) {
            int cidx = k * 64 + lane;
            bool sup = false;
            if (cidx < NCELLS && cidx > i) {
                float xx1 = fmaxf(ix1, bx1[k]), yy1 = fmaxf(iy1, by1[k]);
                float xx2 = fminf(ix2, bx2[k]), yy2 = fminf(iy2, by2[k]);
                float inter = fmaxf(xx2 - xx1, 0.f) * fmaxf(yy2 - yy1, 0.f);
                float iou = inter / (ia + bar[k] - inter + 1e-14f);
                sup = iou > 0.5f;
            }
            unsigned long long m = __ballot(sup);
            if (lane == 0) smask[i][k] = m;
        }
    }
    __syncthreads();
    unsigned long long keep[4];
    #pragma unroll
    for (int k = 0; k < 4; k++) {
        int cidx = k * 64 + lane;
        bool valid = (cidx < NCELLS) && (ssort[cidx] > 0.01f);
        keep[k] = __ballot(valid);
    }
    #pragma unroll
    for (int wi = 0; wi < 4; wi++) {
        int base = wi * 64;
        int lim = (NCELLS - base < 64) ? (NCELLS - base) : 64;
        for (int t = 0; t < lim; t++) {
            if ((keep[wi] >> t) & 1ull) {
                int i = base + t;
                keep[0] &= ~smask[i][0];
                keep[1] &= ~smask[i][1];
                keep[2] &= ~smask[i][2];
                keep[3] &= ~smask[i][3];
            }
        }
    }
    if (j < NCELLS) {
        bool kept = (keep[w] >> lane) & 1ull;
        out[(((size_t)b * NCELLS) + ord[j]) * 24 + 4 + c] = kept ? ssort[j] : 0.f;
    }
}

// ---- launch ----
extern "C" void kernel_launch(void* const* d_in, const int* in_sizes, int n_in,
                              void* d_out, int out_size, void* d_ws, size_t ws_size,
                              hipStream_t stream) {
    const float* x  = (const float*)d_in[0];
    const float* w1 = (const float*)d_in[1];
    const float* w2 = (const float*)d_in[2];
    const float* w3 = (const float*)d_in[3];
    const float* w4 = (const float*)d_in[4];
    const float* w5 = (const float*)d_in[5];
    const float* wh = (const float*)d_in[6];
    float* out = (float*)d_out;
    char* base = (char*)d_ws;

    // region A
    unsigned short* a3h = (unsigned short*)(base);
    unsigned short* a3l = a3h + 6422528;
    float* part4 = (float*)(base + 25690112);               // 2 x 3,211,264 fp32
    float* part5 = (float*)(base);                          // 8 x 802,816 fp32 (a3 dead)
    unsigned short* a5h = (unsigned short*)(base + 51380224);
    unsigned short* a5l = a5h + 802816;
    float* clsb = (float*)(base + 54746240);
    // region B
    unsigned short* a2h = (unsigned short*)(base + 102760448);
    unsigned short* a2l = a2h + 12845056;
    unsigned short* a4h = (unsigned short*)(base + 102760448);  // overlays a2 (dead after conv3)
    unsigned short* a4l = a4h + 3211264;
    // weights
    unsigned short* w2h = (unsigned short*)(base + 154140672);
    unsigned short* w3h = w2h + 73728;
    unsigned short* w4h = w3h + 294912;
    unsigned short* w5h = w4h + 1179648;
    unsigned short* w2l = (unsigned short*)(base + 161955840);
    unsigned short* w3l = w2l + 73728;
    unsigned short* w4l = w3l + 294912;
    unsigned short* w5l = w4l + 1179648;

    prep_all<<<15264, 256, 0, stream>>>(w2, w3, w4, w5,
                                        w2h, w2l, w3h, w3l, w4h, w4l, w5h, w5l);

    // conv1+conv2 fused: 8b * 14*14 tiles = 1568 blocks
    conv2_fused<<<1568, 256, 0, stream>>>(x, w1, w2h, w2l, a2h, a2l);

    conv_mfma<128, 256, 112, 112, 1, false><<<784, 256, 0, stream>>>(
        a2h, a2l, w3h, w3l, a3h, a3l, nullptr);
    conv_mfma<256, 512, 56, 56, 2, true><<<1024, 256, 0, stream>>>(
        a3h, a3l, w4h, w4l, nullptr, nullptr, part4);
    reduceN_split<2><<<3136, 256, 0, stream>>>(part4, a4h, a4l, 3211264);
    conv_mfma<512, 512, 28, 28, 8, true><<<1024, 256, 0, stream>>>(
        a4h, a4l, w5h, w5l, nullptr, nullptr, part5);
    reduceN_split<8><<<784, 256, 0, stream>>>(part5, a5h, a5l, 802816);

    head_decode_kernel<<<392, 256, 0, stream>>>(a5h, a5l, wh, out, clsb);
    nms_kernel<<<160, 256, 0, stream>>>(clsb, out, out);
}